// Round 1
// baseline (1238.637 us; speedup 1.0000x reference)
//
#include <hip/hip_runtime.h>
#include <hip/hip_bf16.h>

// Problem constants (match reference)
#define DIMT 300      // TERM_DIM
#define DPAD 320      // padded to 32
#define NRELS 40
#define RELD 5
#define TILE_M 64     // elements per chunk/workgroup
#define MAX_CHUNKS 8192  // >= 40 + ceil(500000/64) = 7853

typedef __attribute__((ext_vector_type(8))) short bf16x8;
typedef __attribute__((ext_vector_type(4))) float f32x4;

// ---------------- workspace layout (ints) ----------------
// [0..39]    cnt per rel
// [64..103]  cursor per rel
// [128]      n_chunks
// [256..]    desc_rel   [MAX_CHUNKS]
//            desc_start [MAX_CHUNKS]
//            desc_end   [MAX_CHUNKS]
//            sorted     [B]
// byte MT_OFF: Mt bf16 [40][320][320]  (Mt[r][n][j] = sum_i rel[r,i]*assoc[i][j][n])
#define DESC_OFF 256
#define SORTED_OFF (DESC_OFF + 3*MAX_CHUNKS)
#define MT_OFF_BYTES(B) ((((size_t)(SORTED_OFF + (B)) * 4) + 255) & ~(size_t)255)

__global__ void k_init(int* cnt) {
    int t = threadIdx.x;
    if (t < 64) cnt[t] = 0;           // zeros cnt[40] + cursor slack start
    if (t < 64) cnt[64 + t] = 0;      // cursor region
    if (t == 0) cnt[128] = 0;
}

__global__ void k_hist(const int* __restrict__ rels, int n, int* cnt) {
    __shared__ int l[NRELS];
    int t = threadIdx.x;
    if (t < NRELS) l[t] = 0;
    __syncthreads();
    int b = blockIdx.x * 256 + t;
    if (b < n) atomicAdd(&l[rels[b]], 1);
    __syncthreads();
    if (t < NRELS && l[t]) atomicAdd(&cnt[t], l[t]);
}

__global__ void k_scan(const int* __restrict__ cnt, int* cursor, int* n_chunks,
                       int* desc_rel, int* desc_start, int* desc_end) {
    __shared__ int offs[NRELS + 1];
    __shared__ int coff[NRELS + 1];
    if (threadIdx.x == 0) {
        int s = 0, c = 0;
        for (int r = 0; r < NRELS; r++) {
            offs[r] = s; s += cnt[r];
            coff[r] = c; c += (cnt[r] + TILE_M - 1) / TILE_M;
        }
        offs[NRELS] = s; coff[NRELS] = c;
        *n_chunks = c;
    }
    __syncthreads();
    if (threadIdx.x < NRELS) cursor[threadIdx.x] = offs[threadIdx.x];
    for (int r = 0; r < NRELS; r++) {
        int nch = (cnt[r] + TILE_M - 1) / TILE_M;
        int cend = offs[r] + cnt[r];
        for (int c = threadIdx.x; c < nch; c += 256) {
            int st = offs[r] + c * TILE_M;
            desc_rel[coff[r] + c] = r;
            desc_start[coff[r] + c] = st;
            desc_end[coff[r] + c] = min(st + TILE_M, cend);
        }
    }
}

__global__ void k_scatter(const int* __restrict__ rels, int n, int* cursor,
                          int* __restrict__ sorted) {
    __shared__ int l[NRELS];
    __shared__ int base[NRELS];
    int t = threadIdx.x;
    if (t < NRELS) l[t] = 0;
    __syncthreads();
    int b = blockIdx.x * 256 + t;
    int r = -1, loc = 0;
    if (b < n) { r = rels[b]; loc = atomicAdd(&l[r], 1); }
    __syncthreads();
    if (t < NRELS && l[t]) base[t] = atomicAdd(&cursor[t], l[t]);
    __syncthreads();
    if (b < n) sorted[base[r] + loc] = b;
}

// Mt[r][n][j] = sum_i rel_table[r,i] * assoc[i][j][n], zero-padded to 320x320.
// Reads coalesced along n, writes coalesced along j via LDS 32x33 transpose tile.
__global__ void k_build_mt(const float* __restrict__ rel_table,
                           const float* __restrict__ assoc,
                           __hip_bfloat16* __restrict__ Mt) {
    int r = blockIdx.x / 100;
    int t6 = blockIdx.x % 100;
    int tn = (t6 / 10) * 32, tj = (t6 % 10) * 32;
    __shared__ float tile[32][33];
    __shared__ float rw[RELD];
    if (threadIdx.x < RELD) rw[threadIdx.x] = rel_table[r * RELD + threadIdx.x];
    __syncthreads();
    for (int e = threadIdx.x; e < 1024; e += 256) {
        int jl = e >> 5, nl = e & 31;
        int j = tj + jl, n = tn + nl;
        float v = 0.f;
        if (j < DIMT && n < DIMT) {
            #pragma unroll
            for (int i = 0; i < RELD; i++) v += rw[i] * assoc[(i * DIMT + j) * DIMT + n];
        }
        tile[jl][nl] = v;
    }
    __syncthreads();
    for (int e = threadIdx.x; e < 1024; e += 256) {
        int nl = e >> 5, jl = e & 31;
        int n = tn + nl, j = tj + jl;
        Mt[((size_t)r * DPAD + n) * DPAD + j] = __float2bfloat16(tile[jl][nl]);
    }
}

// Grouped GEMM: per chunk of <=64 elements of one relation:
//   X[m,n] = sum_j tL[m][j] * M[j][n]  (bf16 MFMA, fp32 acc)
//   energy[m] = sum_n X[m,n] * tR[m][n]  (fp32 epilogue)
__global__ __launch_bounds__(256) void k_gemm(
    const int* __restrict__ sorted, const int* __restrict__ desc_rel,
    const int* __restrict__ desc_start, const int* __restrict__ desc_end,
    const int* __restrict__ n_chunks,
    const int* __restrict__ terms_L, const int* __restrict__ terms_R,
    const float* __restrict__ term_table, const __hip_bfloat16* __restrict__ Mt,
    float* __restrict__ out) {
    int cid = blockIdx.x;
    if (cid >= *n_chunks) return;
    int rel = desc_rel[cid];
    int start = desc_start[cid];
    int tm = desc_end[cid] - start;

    __shared__ __align__(16) __hip_bfloat16 Alds[TILE_M][32];   // 4 KB
    __shared__ __align__(16) __hip_bfloat16 Blds[DPAD][32];     // 20 KB
    __shared__ int elds[TILE_M];

    int t = threadIdx.x;
    if (t < TILE_M) elds[t] = (t < tm) ? sorted[start + t] : -1;
    __syncthreads();

    int wave = t >> 6, lane = t & 63;
    int quad = lane >> 4, l16 = lane & 15;

    f32x4 acc[20];
    #pragma unroll
    for (int i = 0; i < 20; i++) acc[i] = (f32x4){0.f, 0.f, 0.f, 0.f};

    const __hip_bfloat16* Mtr = Mt + (size_t)rel * DPAD * DPAD;

    // A-staging addressing reused each iter
    int arow = t >> 2, apart = t & 3;
    int ae = elds[arow];
    const float* asrc = (ae >= 0) ? (term_table + (size_t)terms_L[ae] * DIMT) : nullptr;

    for (int kc = 0; kc < 10; kc++) {
        int k0 = kc * 32;
        // stage A: 64 rows x 32 k (gathered tL rows, fp32 -> bf16)
        {
            int kbase = k0 + apart * 8;
            float vals[8];
            if (asrc && kbase + 8 <= DIMT) {
                #pragma unroll
                for (int j = 0; j < 8; j++) vals[j] = asrc[kbase + j];
            } else if (asrc) {
                #pragma unroll
                for (int j = 0; j < 8; j++) vals[j] = (kbase + j < DIMT) ? asrc[kbase + j] : 0.f;
            } else {
                #pragma unroll
                for (int j = 0; j < 8; j++) vals[j] = 0.f;
            }
            __hip_bfloat16* dst = &Alds[arow][apart * 8];
            #pragma unroll
            for (int j = 0; j < 8; j++) dst[j] = __float2bfloat16(vals[j]);
        }
        // stage B: Mt rows [0,320) x 32 k (already bf16, 16B copies)
        for (int idx = t; idx < DPAD * 4; idx += 256) {
            int n = idx >> 2, part = idx & 3;
            *((bf16x8*)&Blds[n][part * 8]) =
                *((const bf16x8*)(Mtr + (size_t)n * DPAD + k0 + part * 8));
        }
        __syncthreads();

        bf16x8 afrag = *((const bf16x8*)&Alds[wave * 16 + l16][quad * 8]);
        #pragma unroll
        for (int nt = 0; nt < 20; nt++) {
            bf16x8 bfrag = *((const bf16x8*)&Blds[nt * 16 + l16][quad * 8]);
            acc[nt] = __builtin_amdgcn_mfma_f32_16x16x32_bf16(afrag, bfrag, acc[nt], 0, 0, 0);
        }
        __syncthreads();
    }

    // Epilogue: lane holds X[row=quad*4+reg][col=l16] per n-tile.
    // energy[m] = sum_n X[m,n]*tR[m][n]; reduce over the 16 cols in each quad.
    #pragma unroll
    for (int reg = 0; reg < 4; reg++) {
        int mrow = wave * 16 + quad * 4 + reg;
        int e = elds[mrow];
        float s = 0.f;
        if (e >= 0) {
            const float* tr = term_table + (size_t)terms_R[e] * DIMT;
            #pragma unroll
            for (int nt = 0; nt < 20; nt++) {
                int n = nt * 16 + l16;
                if (n < DIMT) s += acc[nt][reg] * tr[n];
            }
        }
        s += __shfl_xor(s, 1);
        s += __shfl_xor(s, 2);
        s += __shfl_xor(s, 4);
        s += __shfl_xor(s, 8);
        if (l16 == 0 && e >= 0) out[e] = s;
    }
}

extern "C" void kernel_launch(void* const* d_in, const int* in_sizes, int n_in,
                              void* d_out, int out_size, void* d_ws, size_t ws_size,
                              hipStream_t stream) {
    const int*   rels       = (const int*)d_in[0];
    const int*   terms_L    = (const int*)d_in[1];
    const int*   terms_R    = (const int*)d_in[2];
    const float* term_table = (const float*)d_in[3];
    const float* rel_table  = (const float*)d_in[4];
    const float* assoc      = (const float*)d_in[5];
    float* out = (float*)d_out;
    int B = in_sizes[0];

    int* wsi        = (int*)d_ws;
    int* cnt        = wsi;
    int* cursor     = wsi + 64;
    int* n_chunks   = wsi + 128;
    int* desc_rel   = wsi + DESC_OFF;
    int* desc_start = desc_rel + MAX_CHUNKS;
    int* desc_end   = desc_start + MAX_CHUNKS;
    int* sorted     = wsi + SORTED_OFF;
    __hip_bfloat16* Mt = (__hip_bfloat16*)((char*)d_ws + MT_OFF_BYTES(B));
    // total ws need ~10.3 MB

    int nb = (B + 255) / 256;
    k_init<<<1, 128, 0, stream>>>(cnt);
    k_hist<<<nb, 256, 0, stream>>>(rels, B, cnt);
    k_scan<<<1, 256, 0, stream>>>(cnt, cursor, n_chunks, desc_rel, desc_start, desc_end);
    k_scatter<<<nb, 256, 0, stream>>>(rels, B, cursor, sorted);
    k_build_mt<<<NRELS * 100, 256, 0, stream>>>(rel_table, assoc, Mt);
    k_gemm<<<MAX_CHUNKS, 256, 0, stream>>>(sorted, desc_rel, desc_start, desc_end,
                                           n_chunks, terms_L, terms_R, term_table, Mt, out);
}

// Round 2
// 1069.992 us; speedup vs baseline: 1.1576x; 1.1576x over previous
//
#include <hip/hip_runtime.h>
#include <hip/hip_bf16.h>

// Problem constants (match reference)
#define DIMT 300      // TERM_DIM
#define DPAD 320      // padded to 32
#define NRELS 40
#define RELD 5
#define TILE_M 64     // elements per chunk/workgroup
#define MAX_CHUNKS 8192  // >= 40 + ceil(500000/64) = 7853

typedef __attribute__((ext_vector_type(8))) short bf16x8;
typedef __attribute__((ext_vector_type(4))) float f32x4;

// ---------------- workspace layout (ints) ----------------
#define DESC_OFF 256
#define SORTED_OFF (DESC_OFF + 3*MAX_CHUNKS)
#define MT_OFF_BYTES(B) ((((size_t)(SORTED_OFF + (B)) * 4) + 255) & ~(size_t)255)

__global__ void k_init(int* cnt) {
    int t = threadIdx.x;
    if (t < 64) cnt[t] = 0;
    if (t < 64) cnt[64 + t] = 0;
    if (t == 0) cnt[128] = 0;
}

__global__ void k_hist(const int* __restrict__ rels, int n, int* cnt) {
    __shared__ int l[NRELS];
    int t = threadIdx.x;
    if (t < NRELS) l[t] = 0;
    __syncthreads();
    int b = blockIdx.x * 256 + t;
    if (b < n) atomicAdd(&l[rels[b]], 1);
    __syncthreads();
    if (t < NRELS && l[t]) atomicAdd(&cnt[t], l[t]);
}

__global__ void k_scan(const int* __restrict__ cnt, int* cursor, int* n_chunks,
                       int* desc_rel, int* desc_start, int* desc_end) {
    __shared__ int offs[NRELS + 1];
    __shared__ int coff[NRELS + 1];
    if (threadIdx.x == 0) {
        int s = 0, c = 0;
        for (int r = 0; r < NRELS; r++) {
            offs[r] = s; s += cnt[r];
            coff[r] = c; c += (cnt[r] + TILE_M - 1) / TILE_M;
        }
        offs[NRELS] = s; coff[NRELS] = c;
        *n_chunks = c;
    }
    __syncthreads();
    if (threadIdx.x < NRELS) cursor[threadIdx.x] = offs[threadIdx.x];
    for (int r = 0; r < NRELS; r++) {
        int nch = (cnt[r] + TILE_M - 1) / TILE_M;
        int cend = offs[r] + cnt[r];
        for (int c = threadIdx.x; c < nch; c += 256) {
            int st = offs[r] + c * TILE_M;
            desc_rel[coff[r] + c] = r;
            desc_start[coff[r] + c] = st;
            desc_end[coff[r] + c] = min(st + TILE_M, cend);
        }
    }
}

__global__ void k_scatter(const int* __restrict__ rels, int n, int* cursor,
                          int* __restrict__ sorted) {
    __shared__ int l[NRELS];
    __shared__ int base[NRELS];
    int t = threadIdx.x;
    if (t < NRELS) l[t] = 0;
    __syncthreads();
    int b = blockIdx.x * 256 + t;
    int r = -1, loc = 0;
    if (b < n) { r = rels[b]; loc = atomicAdd(&l[r], 1); }
    __syncthreads();
    if (t < NRELS && l[t]) base[t] = atomicAdd(&cursor[t], l[t]);
    __syncthreads();
    if (b < n) sorted[base[r] + loc] = b;
}

// Mt[r][n][j] = sum_i rel_table[r,i] * assoc[i][j][n], zero-padded to 320x320.
__global__ void k_build_mt(const float* __restrict__ rel_table,
                           const float* __restrict__ assoc,
                           __hip_bfloat16* __restrict__ Mt) {
    int r = blockIdx.x / 100;
    int t6 = blockIdx.x % 100;
    int tn = (t6 / 10) * 32, tj = (t6 % 10) * 32;
    __shared__ float tile[32][33];
    __shared__ float rw[RELD];
    if (threadIdx.x < RELD) rw[threadIdx.x] = rel_table[r * RELD + threadIdx.x];
    __syncthreads();
    for (int e = threadIdx.x; e < 1024; e += 256) {
        int jl = e >> 5, nl = e & 31;
        int j = tj + jl, n = tn + nl;
        float v = 0.f;
        if (j < DIMT && n < DIMT) {
            #pragma unroll
            for (int i = 0; i < RELD; i++) v += rw[i] * assoc[(i * DIMT + j) * DIMT + n];
        }
        tile[jl][nl] = v;
    }
    __syncthreads();
    for (int e = threadIdx.x; e < 1024; e += 256) {
        int nl = e >> 5, jl = e & 31;
        int n = tn + nl, j = tj + jl;
        Mt[((size_t)r * DPAD + n) * DPAD + j] = __float2bfloat16(tile[jl][nl]);
    }
}

// async 16B global -> LDS (direct-to-shared DMA, no VGPR round trip)
__device__ inline void async_g2l16(const void* g, void* l) {
    __builtin_amdgcn_global_load_lds(
        (const __attribute__((address_space(1))) unsigned int*)g,
        (__attribute__((address_space(3))) unsigned int*)l, 16, 0, 0);
}

// Grouped GEMM: per chunk of <=64 elements of one relation:
//   X[m,n] = sum_j tL[m][j] * M[j][n]  (bf16 MFMA, fp32 acc)
//   energy[m] = sum_n X[m,n] * tR[m][n]  (fp32 epilogue)
// A (tL rows) lives in registers for the whole K-loop; B (Mt) is
// double-buffered in LDS via global_load_lds, prefetch issued AFTER the
// barrier so the barrier drain only waits on loads that had a full compute
// phase in flight.
__global__ __launch_bounds__(256, 3) void k_gemm(
    const int* __restrict__ sorted, const int* __restrict__ desc_rel,
    const int* __restrict__ desc_start, const int* __restrict__ desc_end,
    const int* __restrict__ n_chunks,
    const int* __restrict__ terms_L, const int* __restrict__ terms_R,
    const float* __restrict__ term_table, const __hip_bfloat16* __restrict__ Mt,
    float* __restrict__ out) {
    int cid = blockIdx.x;
    if (cid >= *n_chunks) return;
    int rel = desc_rel[cid];
    int start = desc_start[cid];
    int tm = desc_end[cid] - start;

    // B buffer: [buf][n*32 + k] bf16, row = 64B; 2 x 20 KB
    __shared__ __align__(16) __hip_bfloat16 Blds[2][DPAD * 32];
    __shared__ int elds[TILE_M];

    int t = threadIdx.x;
    if (t < TILE_M) elds[t] = (t < tm) ? sorted[start + t] : -1;
    __syncthreads();

    int wave = t >> 6, lane = t & 63;
    int quad = lane >> 4, l16 = lane & 15;

    const __hip_bfloat16* Mtr = Mt + (size_t)rel * DPAD * DPAD;

    // ---- B staging lambda: 20 KB = 1280 x 16B chunks, 5 per thread ----
    auto stage = [&](int kc, int buf) {
        const char* gb = (const char*)Mtr + kc * 64;  // kc*32 bf16 = 64 B
        char* lb = (char*)&Blds[buf][0];
        #pragma unroll
        for (int i = 0; i < 5; i++) {
            int c = t + i * 256;
            async_g2l16(gb + (size_t)(c >> 2) * (DPAD * 2) + (c & 3) * 16,
                        lb + c * 16);
        }
    };

    // kick off B[0] before the (long) A register preload
    stage(0, 0);

    // ---- A preload: each lane holds row elds[wave*16+l16], cols quad*8.. for all 10 kc ----
    int arow = wave * 16 + l16;
    int ae = elds[arow];
    const float* arp = (ae >= 0) ? (term_table + (size_t)terms_L[ae] * DIMT) : nullptr;
    bf16x8 afrag[10];
    #pragma unroll
    for (int kc = 0; kc < 10; kc++) {
        int kb = kc * 32 + quad * 8;
        float v[8];
        if (arp && kb + 8 <= DIMT) {
            float4 p0 = *(const float4*)(arp + kb);
            float4 p1 = *(const float4*)(arp + kb + 4);
            v[0] = p0.x; v[1] = p0.y; v[2] = p0.z; v[3] = p0.w;
            v[4] = p1.x; v[5] = p1.y; v[6] = p1.z; v[7] = p1.w;
        } else if (arp) {
            #pragma unroll
            for (int j = 0; j < 8; j++) v[j] = (kb + j < DIMT) ? arp[kb + j] : 0.f;
        } else {
            #pragma unroll
            for (int j = 0; j < 8; j++) v[j] = 0.f;
        }
        union { bf16x8 v8; __hip_bfloat16 h[8]; } u;
        #pragma unroll
        for (int j = 0; j < 8; j++) u.h[j] = __float2bfloat16(v[j]);
        afrag[kc] = u.v8;
    }

    f32x4 acc[20];
    #pragma unroll
    for (int i = 0; i < 20; i++) acc[i] = (f32x4){0.f, 0.f, 0.f, 0.f};

    __syncthreads();  // drains stage(0) + everyone's A loads

    for (int kc = 0; kc < 10; kc++) {
        int cur = kc & 1;
        if (kc < 9) stage(kc + 1, cur ^ 1);  // async prefetch, after barrier
        const __hip_bfloat16* bb = &Blds[cur][0];
        #pragma unroll
        for (int nt = 0; nt < 20; nt++) {
            bf16x8 bfrag = *((const bf16x8*)(bb + (nt * 16 + l16) * 32 + quad * 8));
            acc[nt] = __builtin_amdgcn_mfma_f32_16x16x32_bf16(afrag[kc], bfrag, acc[nt], 0, 0, 0);
        }
        __syncthreads();  // prefetch had the whole MFMA phase to land
    }

    // Epilogue: lane holds X[row=quad*4+reg][col=l16] per n-tile.
    #pragma unroll
    for (int reg = 0; reg < 4; reg++) {
        int mrow = wave * 16 + quad * 4 + reg;
        int e = elds[mrow];
        float s = 0.f;
        if (e >= 0) {
            const float* tr = term_table + (size_t)terms_R[e] * DIMT;
            #pragma unroll
            for (int nt = 0; nt < 20; nt++) {
                int n = nt * 16 + l16;
                if (n < DIMT) s += acc[nt][reg] * tr[n];
            }
        }
        s += __shfl_xor(s, 1);
        s += __shfl_xor(s, 2);
        s += __shfl_xor(s, 4);
        s += __shfl_xor(s, 8);
        if (l16 == 0 && e >= 0) out[e] = s;
    }
}

extern "C" void kernel_launch(void* const* d_in, const int* in_sizes, int n_in,
                              void* d_out, int out_size, void* d_ws, size_t ws_size,
                              hipStream_t stream) {
    const int*   rels       = (const int*)d_in[0];
    const int*   terms_L    = (const int*)d_in[1];
    const int*   terms_R    = (const int*)d_in[2];
    const float* term_table = (const float*)d_in[3];
    const float* rel_table  = (const float*)d_in[4];
    const float* assoc      = (const float*)d_in[5];
    float* out = (float*)d_out;
    int B = in_sizes[0];

    int* wsi        = (int*)d_ws;
    int* cnt        = wsi;
    int* cursor     = wsi + 64;
    int* n_chunks   = wsi + 128;
    int* desc_rel   = wsi + DESC_OFF;
    int* desc_start = desc_rel + MAX_CHUNKS;
    int* desc_end   = desc_start + MAX_CHUNKS;
    int* sorted     = wsi + SORTED_OFF;
    __hip_bfloat16* Mt = (__hip_bfloat16*)((char*)d_ws + MT_OFF_BYTES(B));

    int nb = (B + 255) / 256;
    k_init<<<1, 128, 0, stream>>>(cnt);
    k_hist<<<nb, 256, 0, stream>>>(rels, B, cnt);
    k_scan<<<1, 256, 0, stream>>>(cnt, cursor, n_chunks, desc_rel, desc_start, desc_end);
    k_scatter<<<nb, 256, 0, stream>>>(rels, B, cursor, sorted);
    k_build_mt<<<NRELS * 100, 256, 0, stream>>>(rel_table, assoc, Mt);
    k_gemm<<<MAX_CHUNKS, 256, 0, stream>>>(sorted, desc_rel, desc_start, desc_end,
                                           n_chunks, terms_L, terms_R, term_table, Mt, out);
}